// Round 5
// baseline (1098.575 us; speedup 1.0000x reference)
//
#include <hip/hip_runtime.h>
#include <cstdint>
#include <cstddef>

#define S_ROWS 4096
#define DIM 1024
#define NE 64
#define CAP 512
#define NEGV -1e9f
#define NGEMM 128           // fused gemm+gating blocks, 32 rows each
#define NFILL 4096          // zero-fill blocks
#define MAGIC 0x1F2E3D4C    // != 0xAAAAAAAA poison

typedef float v4f __attribute__((ext_vector_type(4)));

__device__ __forceinline__ int aloadi(const int* p) {
    return __hip_atomic_load(p, __ATOMIC_RELAXED, __HIP_MEMORY_SCOPE_AGENT);
}
__device__ __forceinline__ float aloadf(const float* p) {
    return __hip_atomic_load(p, __ATOMIC_RELAXED, __HIP_MEMORY_SCOPE_AGENT);
}
__device__ __forceinline__ void astorei(int* p, int v) {
    __hip_atomic_store(p, v, __ATOMIC_RELAXED, __HIP_MEMORY_SCOPE_AGENT);
}
__device__ __forceinline__ void astoref(float* p, float v) {
    __hip_atomic_store(p, v, __ATOMIC_RELAXED, __HIP_MEMORY_SCOPE_AGENT);
}

// ---- kernel A: fill (blocks >= NGEMM) + gemm+gating+rank-lookback+l_aux (blocks < NGEMM) ----
__global__ __launch_bounds__(256) void fusedA(const float* __restrict__ X1, const float* __restrict__ W1,
                                              const float* __restrict__ X2, const float* __restrict__ W2,
                                              int* __restrict__ eidx, float* __restrict__ gval,
                                              int* __restrict__ rnk,
                                              float* __restrict__ Gslot, int* __restrict__ Cslot,
                                              int* __restrict__ flags,
                                              v4f* __restrict__ out4, long long n4,
                                              float* __restrict__ out, long long n) {
    const int bid = blockIdx.x;
    const int tid = threadIdx.x;

    __shared__ float As[32][68];      // [row][k], +4 pad
    __shared__ float Bs[64][68];      // [k][expert]
    __shared__ float Lg[2][32][68];   // logits of both matrices
    __shared__ float sG[4][NE];
    __shared__ int   hist[NE];
    __shared__ int   le[32];          // local expert idx per row
    __shared__ float lv[32];          // local gate val per row

    if (bid >= NGEMM) {
        // ---- streaming zero-fill of d_out; skip out[0..3] (out[0] = l_aux, written by block 127) ----
        long long i = (long long)(bid - NGEMM) * 256 + tid;
        const long long stride = (long long)(gridDim.x - NGEMM) * 256;
        v4f z = {0.f, 0.f, 0.f, 0.f};
        for (; i < n4; i += stride)
            if (i) __builtin_nontemporal_store(z, &out4[i]);
        if (bid == NGEMM && tid == 0) {
            out[1] = 0.f; out[2] = 0.f; out[3] = 0.f;
            for (long long j = n4 * 4; j < n; ++j) out[j] = 0.f;   // 1 tail element
        }
        return;
    }

    // ---- fused gemm (both matrices) + gating for rows [bid*32, bid*32+32) ----
    if (tid < NE) hist[tid] = 0;

    const int row0 = bid * 32;
    const int tx = tid & 15;          // expert quad
    const int ty = tid >> 4;          // row pair

    #pragma unroll
    for (int m = 0; m < 2; ++m) {
        const float* __restrict__ X = m ? X2 : X1;
        const float* __restrict__ W = m ? W2 : W1;
        float acc[2][4] = {};
        for (int kk = 0; kk < DIM; kk += 64) {
            __syncthreads();
            #pragma unroll
            for (int p = 0; p < 2; ++p) {
                int r  = ty + p * 16;
                int c4 = tx * 4;
                float4 a = *(const float4*)&X[(size_t)(row0 + r) * DIM + kk + c4];
                *(float4*)&As[r][c4] = a;
            }
            #pragma unroll
            for (int p = 0; p < 4; ++p) {
                int e  = ty + p * 16;
                int c4 = tx * 4;
                float4 w = *(const float4*)&W[(size_t)e * DIM + kk + c4];
                Bs[c4 + 0][e] = w.x;
                Bs[c4 + 1][e] = w.y;
                Bs[c4 + 2][e] = w.z;
                Bs[c4 + 3][e] = w.w;
            }
            __syncthreads();
            #pragma unroll
            for (int k4 = 0; k4 < 64; k4 += 4) {
                float4 a[2], b[4];
                #pragma unroll
                for (int i = 0; i < 2; ++i) a[i] = *(float4*)&As[ty * 2 + i][k4];
                #pragma unroll
                for (int t = 0; t < 4; ++t) b[t] = *(float4*)&Bs[k4 + t][tx * 4];
                #pragma unroll
                for (int i = 0; i < 2; ++i) {
                    acc[i][0] += a[i].x * b[0].x + a[i].y * b[1].x + a[i].z * b[2].x + a[i].w * b[3].x;
                    acc[i][1] += a[i].x * b[0].y + a[i].y * b[1].y + a[i].z * b[2].y + a[i].w * b[3].y;
                    acc[i][2] += a[i].x * b[0].z + a[i].y * b[1].z + a[i].z * b[2].z + a[i].w * b[3].z;
                    acc[i][3] += a[i].x * b[0].w + a[i].y * b[1].w + a[i].z * b[2].w + a[i].w * b[3].w;
                }
            }
        }
        #pragma unroll
        for (int i = 0; i < 2; ++i)
            #pragma unroll
            for (int t = 0; t < 4; ++t)
                Lg[m][ty * 2 + i][tx * 4 + t] = acc[i][t];
    }
    __syncthreads();   // both logits visible; hist init visible

    // gating: wave w handles local rows w*8 .. w*8+7 ; lane = expert
    const int wid = tid >> 6, lane = tid & 63;
    float gacc = 0.f;
    #pragma unroll
    for (int i = 0; i < 8; ++i) {
        const int lr = wid * 8 + i;
        const int r  = row0 + lr;
        float l1 = Lg[0][lr][lane];
        if (lane == 0) l1 = NEGV;                 // group 0 excluded before softmax

        int cnt = 0;                              // rank (value desc, index asc) -> top-16 set
        #pragma unroll
        for (int j = 0; j < 64; ++j) {
            float vj = __shfl(l1, j);
            cnt += (vj > l1 || (vj == l1 && j < lane));
        }
        const bool sel = cnt < 16;

        float l2 = Lg[1][lr][lane];
        float ml = sel ? l2 : NEGV;

        float mx = ml;
        #pragma unroll
        for (int o = 32; o; o >>= 1) mx = fmaxf(mx, __shfl_xor(mx, o));
        float ex = expf(ml - mx);                 // unselected underflow to exact 0
        float sum = ex;
        #pragma unroll
        for (int o = 32; o; o >>= 1) sum += __shfl_xor(sum, o);
        float g = ex / sum;
        gacc += g;

        float bg = g; int bi = lane;              // argmax, lowest-index tie-break
        #pragma unroll
        for (int o = 32; o; o >>= 1) {
            float og = __shfl_xor(bg, o);
            int   oi = __shfl_xor(bi, o);
            if (og > bg || (og == bg && oi < bi)) { bg = og; bi = oi; }
        }
        if (lane == 0) {
            eidx[r] = bi;                         // consumed by kernel B (after kernel boundary)
            gval[r] = bg;
            le[lr] = bi;
            lv[lr] = bg;
            atomicAdd(&hist[bi], 1);
        }
    }
    sG[wid][lane] = gacc;
    __syncthreads();

    // publish per-block partials (wave 0), then release flag
    if (tid < NE) {
        astoref(&Gslot[bid * NE + tid], sG[0][tid] + sG[1][tid] + sG[2][tid] + sG[3][tid]);
        astorei(&Cslot[bid * NE + tid], hist[tid]);
    }
    __threadfence();                              // drain wave-0 stores, agent-scope
    if (tid == 0)
        __hip_atomic_store(&flags[bid], MAGIC, __ATOMIC_RELEASE, __HIP_MEMORY_SCOPE_AGENT);

    // lookback: wait for all predecessor gemm blocks (fill blocks never wait -> no deadlock)
    for (int b = tid; b < bid; b += 256)
        while (__hip_atomic_load(&flags[b], __ATOMIC_ACQUIRE, __HIP_MEMORY_SCOPE_AGENT) != MAGIC)
            __builtin_amdgcn_s_sleep(1);
    __syncthreads();

    // global rank = prefix over predecessor histograms + intra-block rank
    if (tid < 32) {
        const int e = le[tid];
        int p = 0;
        for (int b = 0; b < bid; ++b) p += aloadi(&Cslot[b * NE + e]);
        for (int j = 0; j < tid; ++j) p += (le[j] == e);
        rnk[row0 + tid] = p;                      // = locations1_s
    }

    // l_aux: block 127 has waited on everyone; reduce and write out[0] (fill skips it)
    if (bid == NGEMM - 1 && tid < NE) {
        float Ge = 0.f; int Ce = 0;
        for (int b = 0; b < NGEMM; ++b) {
            Ge += aloadf(&Gslot[b * NE + tid]);
            Ce += aloadi(&Cslot[b * NE + tid]);
        }
        float v = Ge * (float)Ce;
        #pragma unroll
        for (int o = 32; o; o >>= 1) v += __shfl_xor(v, o);
        // l_aux = sum_e G_e*C_e / (S*S) * (E*E/num_2nd) = sum/65536
        if (tid == 0) out[0] = v * (1.0f / 65536.0f);
    }
}

// ---- kernel B: trivial scatter (must run after fill completes) ----
__global__ __launch_bounds__(256) void scatterB(const int* __restrict__ eidx, const float* __restrict__ gval,
                                                const int* __restrict__ rnk, float* __restrict__ out) {
    const int s = blockIdx.x * 256 + threadIdx.x;
    const int rank = rnk[s];
    if (rank < CAP) {
        const size_t base = 1 + (((size_t)s * NE + eidx[s]) * CAP + (size_t)rank);
        out[base] = gval[s];                                  // combine
        out[base + (size_t)S_ROWS * NE * CAP] = 1.0f;         // dispatch
    }
}

extern "C" void kernel_launch(void* const* d_in, const int* in_sizes, int n_in,
                              void* d_out, int out_size, void* d_ws, size_t ws_size,
                              hipStream_t stream) {
    const float* in1 = (const float*)d_in[0];
    const float* in2 = (const float*)d_in[1];
    const float* wg1 = (const float*)d_in[2];
    const float* wg2 = (const float*)d_in[3];
    float* out = (float*)d_out;

    int*   eidx  = (int*)d_ws;                          // [4096]
    float* gv    = (float*)(eidx + S_ROWS);             // [4096]
    int*   rnk   = (int*)(gv + S_ROWS);                 // [4096]
    float* Gslot = (float*)(rnk + S_ROWS);              // [128*64]
    int*   Cslot = (int*)(Gslot + NGEMM * NE);          // [128*64]
    int*   flags = Cslot + NGEMM * NE;                  // [128]

    long long n  = (long long)out_size;
    long long n4 = n >> 2;

    fusedA<<<NGEMM + NFILL, 256, 0, stream>>>(in1, wg1, in2, wg2,
                                              eidx, gv, rnk, Gslot, Cslot, flags,
                                              (v4f*)out, n4, out, n);
    scatterB<<<S_ROWS / 256, 256, 0, stream>>>(eidx, gv, rnk, out);
}

// Round 6
// 1085.415 us; speedup vs baseline: 1.0121x; 1.0121x over previous
//
#include <hip/hip_runtime.h>
#include <cstdint>
#include <cstddef>

#define S_ROWS 4096
#define DIM 1024
#define NE 64
#define CAP 512
#define NEGV -1e9f
#define NGEMM 128           // fused gemm+gating blocks, 32 rows each
#define NFILL 4096          // zero-fill blocks

typedef float v4f __attribute__((ext_vector_type(4)));

// ---- kernel A: zero-fill (blocks >= NGEMM) + fused gemm+gating (blocks < NGEMM) ----
__global__ __launch_bounds__(256) void fusedA(const float* __restrict__ X1, const float* __restrict__ W1,
                                              const float* __restrict__ X2, const float* __restrict__ W2,
                                              int* __restrict__ eidx, float* __restrict__ gval,
                                              float* __restrict__ Gslot, int* __restrict__ Cslot,
                                              v4f* __restrict__ out4, long long n4,
                                              float* __restrict__ out, long long n) {
    const int bid = blockIdx.x;
    const int tid = threadIdx.x;

    __shared__ float As[32][68];      // [row][k], +4 pad
    __shared__ float Bs[64][68];      // [k][expert]
    __shared__ float Lg[2][32][68];   // logits of both matrices
    __shared__ float sG[4][NE];
    __shared__ int   hist[NE];

    if (bid >= NGEMM) {
        // ---- streaming zero-fill of d_out (structural 1.07 GB write), branch-free hot loop ----
        long long i = (long long)(bid - NGEMM) * 256 + tid;
        const long long stride = (long long)(gridDim.x - NGEMM) * 256;
        v4f z = {0.f, 0.f, 0.f, 0.f};
        for (; i < n4; i += stride) __builtin_nontemporal_store(z, &out4[i]);
        if (bid == NGEMM && tid == 0)
            for (long long j = n4 * 4; j < n; ++j) out[j] = 0.f;   // 1 tail element
        return;
    }

    // ---- fused gemm (both matrices) + gating for rows [bid*32, bid*32+32) ----
    if (tid < NE) hist[tid] = 0;

    const int row0 = bid * 32;
    const int tx = tid & 15;          // expert quad
    const int ty = tid >> 4;          // row pair

    #pragma unroll
    for (int m = 0; m < 2; ++m) {
        const float* __restrict__ X = m ? X2 : X1;
        const float* __restrict__ W = m ? W2 : W1;
        float acc[2][4] = {};
        for (int kk = 0; kk < DIM; kk += 64) {
            __syncthreads();
            #pragma unroll
            for (int p = 0; p < 2; ++p) {
                int r  = ty + p * 16;
                int c4 = tx * 4;
                float4 a = *(const float4*)&X[(size_t)(row0 + r) * DIM + kk + c4];
                *(float4*)&As[r][c4] = a;
            }
            #pragma unroll
            for (int p = 0; p < 4; ++p) {
                int e  = ty + p * 16;
                int c4 = tx * 4;
                float4 w = *(const float4*)&W[(size_t)e * DIM + kk + c4];
                Bs[c4 + 0][e] = w.x;
                Bs[c4 + 1][e] = w.y;
                Bs[c4 + 2][e] = w.z;
                Bs[c4 + 3][e] = w.w;
            }
            __syncthreads();
            #pragma unroll
            for (int k4 = 0; k4 < 64; k4 += 4) {
                float4 a[2], b[4];
                #pragma unroll
                for (int i = 0; i < 2; ++i) a[i] = *(float4*)&As[ty * 2 + i][k4];
                #pragma unroll
                for (int t = 0; t < 4; ++t) b[t] = *(float4*)&Bs[k4 + t][tx * 4];
                #pragma unroll
                for (int i = 0; i < 2; ++i) {
                    acc[i][0] += a[i].x * b[0].x + a[i].y * b[1].x + a[i].z * b[2].x + a[i].w * b[3].x;
                    acc[i][1] += a[i].x * b[0].y + a[i].y * b[1].y + a[i].z * b[2].y + a[i].w * b[3].y;
                    acc[i][2] += a[i].x * b[0].z + a[i].y * b[1].z + a[i].z * b[2].z + a[i].w * b[3].z;
                    acc[i][3] += a[i].x * b[0].w + a[i].y * b[1].w + a[i].z * b[2].w + a[i].w * b[3].w;
                }
            }
        }
        #pragma unroll
        for (int i = 0; i < 2; ++i)
            #pragma unroll
            for (int t = 0; t < 4; ++t)
                Lg[m][ty * 2 + i][tx * 4 + t] = acc[i][t];
    }
    __syncthreads();   // both logits visible; hist init visible

    // gating: wave w handles local rows w*8 .. w*8+7 ; lane = expert
    const int wid = tid >> 6, lane = tid & 63;
    float gacc = 0.f;
    #pragma unroll
    for (int i = 0; i < 8; ++i) {
        const int lr = wid * 8 + i;
        const int r  = row0 + lr;
        float l1 = Lg[0][lr][lane];
        if (lane == 0) l1 = NEGV;                 // group 0 excluded before softmax

        int cnt = 0;                              // rank (value desc, index asc) -> top-16 set
        #pragma unroll
        for (int j = 0; j < 64; ++j) {
            float vj = __shfl(l1, j);
            cnt += (vj > l1 || (vj == l1 && j < lane));
        }
        const bool sel = cnt < 16;

        float l2 = Lg[1][lr][lane];
        float ml = sel ? l2 : NEGV;

        float mx = ml;
        #pragma unroll
        for (int o = 32; o; o >>= 1) mx = fmaxf(mx, __shfl_xor(mx, o));
        float ex = expf(ml - mx);                 // unselected underflow to exact 0
        float sum = ex;
        #pragma unroll
        for (int o = 32; o; o >>= 1) sum += __shfl_xor(sum, o);
        float g = ex / sum;
        gacc += g;

        float bg = g; int bi = lane;              // argmax, lowest-index tie-break
        #pragma unroll
        for (int o = 32; o; o >>= 1) {
            float og = __shfl_xor(bg, o);
            int   oi = __shfl_xor(bi, o);
            if (og > bg || (og == bg && oi < bi)) { bg = og; bi = oi; }
        }
        if (lane == 0) {
            eidx[r] = bi;
            gval[r] = bg;
            atomicAdd(&hist[bi], 1);
        }
    }
    sG[wid][lane] = gacc;
    __syncthreads();
    if (tid < NE) {
        Gslot[bid * NE + tid] = sG[0][tid] + sG[1][tid] + sG[2][tid] + sG[3][tid];
        Cslot[bid * NE + tid] = hist[tid];
    }
}

// ---- kernel B: blocks 0..127 = rank-from-histogram + scatter (32 rows each); block 128 = l_aux ----
__global__ __launch_bounds__(64) void finishB(const int* __restrict__ eidx, const float* __restrict__ gval,
                                              const float* __restrict__ Gslot, const int* __restrict__ Cslot,
                                              float* __restrict__ out) {
    const int bid = blockIdx.x;
    const int tid = threadIdx.x;    // 64 threads

    if (bid == NGEMM) {
        // l_aux = sum_e G_e*C_e / (S*S) * (E*E/num_2nd) = sum/65536
        float Ge = 0.f; int Ce = 0;
        for (int b = 0; b < NGEMM; ++b) {
            Ge += Gslot[b * NE + tid];
            Ce += Cslot[b * NE + tid];
        }
        float v = Ge * (float)Ce;
        #pragma unroll
        for (int o = 32; o; o >>= 1) v += __shfl_xor(v, o);
        if (tid == 0) out[0] = v * (1.0f / 65536.0f);
        return;
    }

    // per-expert count of tokens routed in tiles before this one (lane = expert)
    int pre = 0;
    for (int b = 0; b < bid; ++b) pre += Cslot[b * NE + tid];

    __shared__ int le[32];
    __shared__ int pref[NE];
    pref[tid] = pre;
    if (tid < 32) le[tid] = eidx[bid * 32 + tid];
    __syncthreads();

    if (tid < 32) {
        const int e = le[tid];
        int rank = pref[e];
        for (int j = 0; j < tid; ++j) rank += (le[j] == e);   // intra-tile stable rank
        if (rank < CAP) {
            const int s = bid * 32 + tid;
            const size_t base = 1 + (((size_t)s * NE + e) * CAP + (size_t)rank);
            out[base] = gval[s];                                  // combine
            out[base + (size_t)S_ROWS * NE * CAP] = 1.0f;         // dispatch
        }
    }
}

extern "C" void kernel_launch(void* const* d_in, const int* in_sizes, int n_in,
                              void* d_out, int out_size, void* d_ws, size_t ws_size,
                              hipStream_t stream) {
    const float* in1 = (const float*)d_in[0];
    const float* in2 = (const float*)d_in[1];
    const float* wg1 = (const float*)d_in[2];
    const float* wg2 = (const float*)d_in[3];
    float* out = (float*)d_out;

    int*   eidx  = (int*)d_ws;                          // [4096]
    float* gv    = (float*)(eidx + S_ROWS);             // [4096]
    float* Gslot = gv + S_ROWS;                         // [128*64]
    int*   Cslot = (int*)(Gslot + NGEMM * NE);          // [128*64]

    long long n  = (long long)out_size;
    long long n4 = n >> 2;

    fusedA<<<NGEMM + NFILL, 256, 0, stream>>>(in1, wg1, in2, wg2,
                                              eidx, gv, Gslot, Cslot,
                                              (v4f*)out, n4, out, n);
    finishB<<<NGEMM + 1, 64, 0, stream>>>(eidx, gv, Gslot, Cslot, out);
}